// Round 5
// baseline (1111.918 us; speedup 1.0000x reference)
//
#include <hip/hip_runtime.h>

#define N_NODES 100000
#define IN_F    256
#define OUT_F   64
#define D_CH    4
#define N_EDGE  800000
#define M_SEG   (D_CH * N_NODES)          // 400000 segments
#define CPW     8                          // chains per wave (3-stage pipeline)

typedef __attribute__((ext_vector_type(8))) short short8;
typedef __attribute__((ext_vector_type(4))) float f32x4;

__device__ inline ushort f2bf(float f) {           // round-to-nearest-even
    union { float f; unsigned u; } v; v.f = f;
    unsigned b = v.u + 0x7FFFu + ((v.u >> 16) & 1u);
    return (ushort)(b >> 16);
}
__device__ inline float bf2f(ushort u) {
    union { unsigned u; float f; } v; v.u = ((unsigned)u) << 16;
    return v.f;
}

// ---------------------------------------------------------------------------
// One-time: repack W (f32) into per-lane bf16 MFMA B-fragments.
// Fragment (i, ks, nt): lane l, elem j holds W[i][ks*32 + (l>>4)*8 + j][nt*16 + (l&15)]
// ---------------------------------------------------------------------------
__global__ __launch_bounds__(256) void bpack_kernel(
    const float* __restrict__ W, ushort* __restrict__ Bpack)
{
    const int t = blockIdx.x * 256 + threadIdx.x;      // 0 .. 8191
    if (t >= D_CH * 8 * 4 * 64) return;
    const int l  = t & 63;
    const int nt = (t >> 6) & 3;
    const int ks = (t >> 8) & 7;
    const int i  = t >> 11;
    const int n  = nt * 16 + (l & 15);
    const int k0 = ks * 32 + (l >> 4) * 8;
    ushort v[8];
#pragma unroll
    for (int j = 0; j < 8; ++j)
        v[j] = f2bf(W[((size_t)i * IN_F + k0 + j) * OUT_F + n]);
#pragma unroll
    for (int j = 0; j < 8; ++j)
        Bpack[(size_t)t * 8 + j] = v[j];
}

// ---------------------------------------------------------------------------
// MFMA GEMM + fused pvec epilogue.  (unchanged from R4)
// C/D layout (HW-verified): col = lane&15, row = (lane>>4)*4 + reg.
// ---------------------------------------------------------------------------
__global__ __launch_bounds__(256) void gemm_mfma_kernel(
    const float* __restrict__ feature, const float* __restrict__ norm,
    const ushort* __restrict__ Bpack, const float* __restrict__ att_w,
    ushort* __restrict__ Wh_b, float* __restrict__ p_src, float* __restrict__ p_dst)
{
    const int wv   = threadIdx.x >> 6;
    const int lane = threadIdx.x & 63;
    const int kg   = lane >> 4;
    const int cl   = lane & 15;
    const int r0   = blockIdx.x * 64 + wv * 16;

    const int rowm   = r0 + cl;
    const int rclamp = (rowm < N_NODES) ? rowm : (N_NODES - 1);
    const float* __restrict__ arow = feature + (size_t)rclamp * IN_F + kg * 8;
    short8 afrag[8];
#pragma unroll
    for (int ks = 0; ks < 8; ++ks) {
        const f32x4 x = *(const f32x4*)(arow + ks * 32);
        const f32x4 y = *(const f32x4*)(arow + ks * 32 + 4);
        short8 a;
        a[0] = (short)f2bf(x[0]); a[1] = (short)f2bf(x[1]);
        a[2] = (short)f2bf(x[2]); a[3] = (short)f2bf(x[3]);
        a[4] = (short)f2bf(y[0]); a[5] = (short)f2bf(y[1]);
        a[6] = (short)f2bf(y[2]); a[7] = (short)f2bf(y[3]);
        afrag[ks] = a;
    }

    float pa[4], pb[4];
#pragma unroll
    for (int nt = 0; nt < 4; ++nt) {
        pa[nt] = att_w[nt * 16 + cl];
        pb[nt] = att_w[OUT_F + nt * 16 + cl];
    }
    float nm[4];
    bool  rvld[4];
#pragma unroll
    for (int r = 0; r < 4; ++r) {
        const int rr = r0 + kg * 4 + r;
        rvld[r] = rr < N_NODES;
        nm[r] = rvld[r] ? norm[rr] : 0.f;
    }

    const short8* __restrict__ bp = (const short8*)Bpack;

    for (int i = 0; i < D_CH; ++i) {
        f32x4 acc[4];
#pragma unroll
        for (int nt = 0; nt < 4; ++nt) acc[nt] = (f32x4){0.f, 0.f, 0.f, 0.f};

#pragma unroll
        for (int ks = 0; ks < 8; ++ks) {
#pragma unroll
            for (int nt = 0; nt < 4; ++nt) {
                const short8 bf = bp[((((i * 8) + ks) * 4 + nt) << 6) + lane];
                acc[nt] = __builtin_amdgcn_mfma_f32_16x16x32_bf16(
                    afrag[ks], bf, acc[nt], 0, 0, 0);
            }
        }

        float ps[4] = {0.f, 0.f, 0.f, 0.f}, pd[4] = {0.f, 0.f, 0.f, 0.f};
#pragma unroll
        for (int nt = 0; nt < 4; ++nt) {
#pragma unroll
            for (int r = 0; r < 4; ++r) {
                const float v = acc[nt][r] * nm[r];
                const int rr = r0 + kg * 4 + r;
                if (rvld[r])
                    Wh_b[((size_t)i * N_NODES + rr) * OUT_F + nt * 16 + cl] = f2bf(v);
                ps[r] += v * pa[nt];
                pd[r] += v * pb[nt];
            }
        }
#pragma unroll
        for (int r = 0; r < 4; ++r) {
            float s1 = ps[r], s2 = pd[r];
#pragma unroll
            for (int off = 1; off < 16; off <<= 1) {
                s1 += __shfl_xor(s1, off, 64);
                s2 += __shfl_xor(s2, off, 64);
            }
            if (cl == 0 && rvld[r]) {
                const int rr = r0 + kg * 4 + r;
                p_src[i * N_NODES + rr] = s1;
                p_dst[i * N_NODES + rr] = s2;
            }
        }
    }
}

// ---------------------------------------------------------------------------
// Linked-list build: next[i][e] = atomicExch(&head[i][dst], e).
// ---------------------------------------------------------------------------
__global__ __launch_bounds__(256) void build_kernel(
    const int* __restrict__ dst, int* __restrict__ head, int* __restrict__ next)
{
    const int e = blockIdx.x * 256 + threadIdx.x;
    const int i = blockIdx.y;
    const int d = dst[(size_t)i * N_EDGE + e];
    const int old = atomicExch(&head[i * N_NODES + d], e);
    next[(size_t)i * N_EDGE + e] = old;
}

// ---------------------------------------------------------------------------
// Aggregate via linked lists, 3-stage software pipeline over CPW=8 chains:
//   stage A (iter k):  issue src[e], next[e]
//   stage B (iter k+1): s resolved -> issue p_src[s], Wh[s] gather
//   stage C (iter k+2): compute exp/leaky, accumulate
// One load-latency per iteration instead of two; ~24 loads in flight/wave.
// Invalid chains load clamped index 0 (L1-hit) and cndmask their weight to 0.
// ---------------------------------------------------------------------------
__global__ __launch_bounds__(256) void agg_ll_kernel(
    const int* __restrict__ head, const int* __restrict__ next,
    const int* __restrict__ src, const float* __restrict__ p_src,
    const float* __restrict__ p_dst, const ushort* __restrict__ Wh_b,
    const float* __restrict__ norm, float* __restrict__ out)
{
    const int wv   = threadIdx.x >> 6;
    const int lane = threadIdx.x & 63;
    const int g0   = (blockIdx.x * 4 + wv) * CPW;   // 8 consecutive segments
    // N_NODES % CPW == 0 -> all CPW segments share one channel.
    const int i  = g0 / N_NODES;
    const int n0 = g0 - i * N_NODES;

    const int*    __restrict__ srcb = src  + (size_t)i * N_EDGE;
    const int*    __restrict__ nxtb = next + (size_t)i * N_EDGE;
    const float*  __restrict__ psb  = p_src + i * N_NODES;
    const ushort* __restrict__ whb  = Wh_b + (size_t)i * N_NODES * OUT_F + lane;

    int   e2[CPW], s1[CPW];
    int   v1[CPW], v0[CPW];
    float ps0[CPW], wh0[CPW], pd[CPW], acc[CPW], z[CPW];
#pragma unroll
    for (int c = 0; c < CPW; ++c) {
        e2[c] = head[g0 + c];
        pd[c] = p_dst[g0 + c];
        s1[c] = 0; v1[c] = 0; v0[c] = 0;
        ps0[c] = 0.f; wh0[c] = 0.f; acc[c] = 0.f; z[c] = 0.f;
    }

    for (;;) {
        int pending = 0;
#pragma unroll
        for (int c = 0; c < CPW; ++c) {
            // ---- stage C: compute with operands loaded 1 iter ago ----
            float x = ps0[c] + pd[c];
            x = (x > 0.f) ? x : 0.2f * x;
            float w = __expf(x);              // max-free softmax: logits O(4)
            w = v0[c] ? w : 0.f;
            acc[c] += w * wh0[c];
            z[c]   += w;
            // ---- stage B -> C: issue dependent data loads for s1 ----
            const int sc = s1[c];
            ps0[c] = psb[sc];
            wh0[c] = bf2f(whb[(size_t)sc * OUT_F]);
            v0[c]  = v1[c];
            // ---- stage A -> B: ingest edge e2, hop ----
            const int live = (e2[c] >= 0);
            const int ec   = live ? e2[c] : 0;
            const int sn   = srcb[ec];
            const int nn   = nxtb[ec];
            v1[c] = live;
            s1[c] = live ? sn : 0;
            e2[c] = live ? nn : -1;
            pending |= v0[c] | v1[c] | (e2[c] >= 0 ? 1 : 0);
        }
        if (!pending) break;
    }

#pragma unroll
    for (int c = 0; c < CPW; ++c) {
        const int n = n0 + c;
        float v = (z[c] > 0.f) ? (acc[c] / z[c]) * norm[n] : 0.f;
        out[(size_t)n * (D_CH * OUT_F) + i * OUT_F + lane] = (v > 0.f) ? v : 0.f;
    }
}

// ---------------------------------------------------------------------------
extern "C" void kernel_launch(void* const* d_in, const int* in_sizes, int n_in,
                              void* d_out, int out_size, void* d_ws, size_t ws_size,
                              hipStream_t stream)
{
    const float* feature = (const float*)d_in[0];
    const float* norm    = (const float*)d_in[1];
    const float* W       = (const float*)d_in[2];
    const float* att_w   = (const float*)d_in[3];
    const int*   src     = (const int*)d_in[4];
    const int*   dst     = (const int*)d_in[5];
    float* out = (float*)d_out;

    // Workspace layout:
    // Wh_b[25.6M u16 = 51.2MB] | p_src[400K f] | p_dst[400K f] |
    // head[400K i] | next[3.2M i] | Bpack[65536 u16]     total ~= 69 MB
    ushort* Wh_b  = (ushort*)d_ws;
    float*  p_src = (float*)(Wh_b + (size_t)M_SEG * OUT_F);
    float*  p_dst = p_src + M_SEG;
    int*    head  = (int*)(p_dst + M_SEG);
    int*    next  = head + M_SEG;
    ushort* Bpack = (ushort*)(next + (size_t)D_CH * N_EDGE);

    bpack_kernel<<<dim3(32), 256, 0, stream>>>(W, Bpack);
    gemm_mfma_kernel<<<dim3((N_NODES + 63) / 64), 256, 0, stream>>>(
        feature, norm, Bpack, att_w, Wh_b, p_src, p_dst);

    hipMemsetAsync(head, 0xFF, (size_t)M_SEG * sizeof(int), stream);  // head = -1
    build_kernel<<<dim3(N_EDGE / 256, D_CH), 256, 0, stream>>>(dst, head, next);
    agg_ll_kernel<<<dim3(M_SEG / (4 * CPW)), 256, 0, stream>>>(
        head, next, src, p_src, p_dst, Wh_b, norm, out);
}

// Round 6
// 440.969 us; speedup vs baseline: 2.5215x; 2.5215x over previous
//
#include <hip/hip_runtime.h>

#define N_NODES 100000
#define IN_F    256
#define OUT_F   64
#define D_CH    4
#define N_EDGE  800000
#define M_SEG   (D_CH * N_NODES)          // 400000 segments
#define CPW     4                          // chains per wave

typedef __attribute__((ext_vector_type(8))) short short8;
typedef __attribute__((ext_vector_type(4))) float f32x4;

__device__ inline ushort f2bf(float f) {           // round-to-nearest-even
    union { float f; unsigned u; } v; v.f = f;
    unsigned b = v.u + 0x7FFFu + ((v.u >> 16) & 1u);
    return (ushort)(b >> 16);
}
__device__ inline float bf2f(ushort u) {
    union { unsigned u; float f; } v; v.u = ((unsigned)u) << 16;
    return v.f;
}

// ---------------------------------------------------------------------------
// One-time: repack W (f32) into per-lane bf16 MFMA B-fragments.
// Fragment (i, ks, nt): lane l, elem j holds W[i][ks*32 + (l>>4)*8 + j][nt*16 + (l&15)]
// ---------------------------------------------------------------------------
__global__ __launch_bounds__(256) void bpack_kernel(
    const float* __restrict__ W, ushort* __restrict__ Bpack)
{
    const int t = blockIdx.x * 256 + threadIdx.x;      // 0 .. 8191
    if (t >= D_CH * 8 * 4 * 64) return;
    const int l  = t & 63;
    const int nt = (t >> 6) & 3;
    const int ks = (t >> 8) & 7;
    const int i  = t >> 11;
    const int n  = nt * 16 + (l & 15);
    const int k0 = ks * 32 + (l >> 4) * 8;
    ushort v[8];
#pragma unroll
    for (int j = 0; j < 8; ++j)
        v[j] = f2bf(W[((size_t)i * IN_F + k0 + j) * OUT_F + n]);
#pragma unroll
    for (int j = 0; j < 8; ++j)
        Bpack[(size_t)t * 8 + j] = v[j];
}

// ---------------------------------------------------------------------------
// MFMA GEMM + fused pvec epilogue.  (unchanged from R4)
// C/D layout (HW-verified): col = lane&15, row = (lane>>4)*4 + reg.
// ---------------------------------------------------------------------------
__global__ __launch_bounds__(256) void gemm_mfma_kernel(
    const float* __restrict__ feature, const float* __restrict__ norm,
    const ushort* __restrict__ Bpack, const float* __restrict__ att_w,
    ushort* __restrict__ Wh_b, float* __restrict__ p_src, float* __restrict__ p_dst)
{
    const int wv   = threadIdx.x >> 6;
    const int lane = threadIdx.x & 63;
    const int kg   = lane >> 4;
    const int cl   = lane & 15;
    const int r0   = blockIdx.x * 64 + wv * 16;

    const int rowm   = r0 + cl;
    const int rclamp = (rowm < N_NODES) ? rowm : (N_NODES - 1);
    const float* __restrict__ arow = feature + (size_t)rclamp * IN_F + kg * 8;
    short8 afrag[8];
#pragma unroll
    for (int ks = 0; ks < 8; ++ks) {
        const f32x4 x = *(const f32x4*)(arow + ks * 32);
        const f32x4 y = *(const f32x4*)(arow + ks * 32 + 4);
        short8 a;
        a[0] = (short)f2bf(x[0]); a[1] = (short)f2bf(x[1]);
        a[2] = (short)f2bf(x[2]); a[3] = (short)f2bf(x[3]);
        a[4] = (short)f2bf(y[0]); a[5] = (short)f2bf(y[1]);
        a[6] = (short)f2bf(y[2]); a[7] = (short)f2bf(y[3]);
        afrag[ks] = a;
    }

    float pa[4], pb[4];
#pragma unroll
    for (int nt = 0; nt < 4; ++nt) {
        pa[nt] = att_w[nt * 16 + cl];
        pb[nt] = att_w[OUT_F + nt * 16 + cl];
    }
    float nm[4];
    bool  rvld[4];
#pragma unroll
    for (int r = 0; r < 4; ++r) {
        const int rr = r0 + kg * 4 + r;
        rvld[r] = rr < N_NODES;
        nm[r] = rvld[r] ? norm[rr] : 0.f;
    }

    const short8* __restrict__ bp = (const short8*)Bpack;

    for (int i = 0; i < D_CH; ++i) {
        f32x4 acc[4];
#pragma unroll
        for (int nt = 0; nt < 4; ++nt) acc[nt] = (f32x4){0.f, 0.f, 0.f, 0.f};

#pragma unroll
        for (int ks = 0; ks < 8; ++ks) {
#pragma unroll
            for (int nt = 0; nt < 4; ++nt) {
                const short8 bf = bp[((((i * 8) + ks) * 4 + nt) << 6) + lane];
                acc[nt] = __builtin_amdgcn_mfma_f32_16x16x32_bf16(
                    afrag[ks], bf, acc[nt], 0, 0, 0);
            }
        }

        float ps[4] = {0.f, 0.f, 0.f, 0.f}, pd[4] = {0.f, 0.f, 0.f, 0.f};
#pragma unroll
        for (int nt = 0; nt < 4; ++nt) {
#pragma unroll
            for (int r = 0; r < 4; ++r) {
                const float v = acc[nt][r] * nm[r];
                const int rr = r0 + kg * 4 + r;
                if (rvld[r])
                    Wh_b[((size_t)i * N_NODES + rr) * OUT_F + nt * 16 + cl] = f2bf(v);
                ps[r] += v * pa[nt];
                pd[r] += v * pb[nt];
            }
        }
#pragma unroll
        for (int r = 0; r < 4; ++r) {
            float s1 = ps[r], s2 = pd[r];
#pragma unroll
            for (int off = 1; off < 16; off <<= 1) {
                s1 += __shfl_xor(s1, off, 64);
                s2 += __shfl_xor(s2, off, 64);
            }
            if (cl == 0 && rvld[r]) {
                const int rr = r0 + kg * 4 + r;
                p_src[i * N_NODES + rr] = s1;
                p_dst[i * N_NODES + rr] = s2;
            }
        }
    }
}

// ---------------------------------------------------------------------------
// Linked-list build with packed records: rec[i][e] = {next, src}.
// rec writes are SEQUENTIAL 8B (e-indexed); only head (1.6 MB, L2) is random.
// ---------------------------------------------------------------------------
__global__ __launch_bounds__(256) void build_kernel(
    const int* __restrict__ src, const int* __restrict__ dst,
    int* __restrict__ head, int2* __restrict__ rec)
{
    const int e = blockIdx.x * 256 + threadIdx.x;
    const int i = blockIdx.y;
    const int d = dst[(size_t)i * N_EDGE + e];
    const int s = src[(size_t)i * N_EDGE + e];
    const int old = atomicExch(&head[i * N_NODES + d], e);
    rec[(size_t)i * N_EDGE + e] = make_int2(old, s);
}

// ---------------------------------------------------------------------------
// Aggregate via linked lists, 4 chains/wave, ONE wait point per iteration.
// Register state entering iteration k: s_k (current src), e_{k+1} (next edge),
// both decoded from rec loaded at k-1. Iteration k issues THREE independent
// loads -- psb[s_k], whb[s_k], rec[e_{k+1}] -- then waits once, accumulates,
// advances. 3 random ops/edge (was 4), 1 exposed latency/iter (was 2).
// ---------------------------------------------------------------------------
__global__ __launch_bounds__(256) void agg_ll_kernel(
    const int* __restrict__ head, const int2* __restrict__ rec,
    const float* __restrict__ p_src, const float* __restrict__ p_dst,
    const ushort* __restrict__ Wh_b, const float* __restrict__ norm,
    float* __restrict__ out)
{
    const int wv   = threadIdx.x >> 6;
    const int lane = threadIdx.x & 63;
    const int g0   = (blockIdx.x * 4 + wv) * CPW;   // 4 consecutive segments
    // N_NODES % CPW == 0 -> all CPW segments share one channel.
    const int i  = g0 / N_NODES;
    const int n0 = g0 - i * N_NODES;

    const int2*   __restrict__ recb = rec + (size_t)i * N_EDGE;
    const float*  __restrict__ psb  = p_src + i * N_NODES;
    const ushort* __restrict__ whb  = Wh_b + (size_t)i * N_NODES * OUT_F + lane;

    // ---- prologue: load rec of the head edge of each chain ----
    int   vld[CPW], s[CPW], en[CPW];
    float pd[CPW], acc[CPW], z[CPW];
#pragma unroll
    for (int c = 0; c < CPW; ++c) {
        const int h = head[g0 + c];
        pd[c]  = p_dst[g0 + c];
        acc[c] = 0.f;
        z[c]   = 0.f;
        const int2 r = recb[(h >= 0) ? h : 0];
        vld[c] = (h >= 0);
        s[c]   = vld[c] ? r.y : 0;
        en[c]  = vld[c] ? r.x : -1;
    }

    for (;;) {
        int pending = 0;
#pragma unroll
        for (int c = 0; c < CPW; ++c) {
            // three independent loads -> single wait covers all
            const float ps = psb[s[c]];
            const float wh = bf2f(whb[(size_t)s[c] * OUT_F]);
            const int2  r  = recb[(en[c] >= 0) ? en[c] : 0];

            float x = ps + pd[c];
            x = (x > 0.f) ? x : 0.2f * x;
            float w = __expf(x);              // max-free softmax: logits O(4)
            w = vld[c] ? w : 0.f;
            acc[c] += w * wh;
            z[c]   += w;

            const int live = (en[c] >= 0);
            vld[c] = live;
            s[c]   = live ? r.y : 0;
            en[c]  = live ? r.x : -1;
            pending |= live;
        }
        if (!pending) break;
    }

#pragma unroll
    for (int c = 0; c < CPW; ++c) {
        const int n = n0 + c;
        float v = (z[c] > 0.f) ? (acc[c] / z[c]) * norm[n] : 0.f;
        out[(size_t)n * (D_CH * OUT_F) + i * OUT_F + lane] = (v > 0.f) ? v : 0.f;
    }
}

// ---------------------------------------------------------------------------
extern "C" void kernel_launch(void* const* d_in, const int* in_sizes, int n_in,
                              void* d_out, int out_size, void* d_ws, size_t ws_size,
                              hipStream_t stream)
{
    const float* feature = (const float*)d_in[0];
    const float* norm    = (const float*)d_in[1];
    const float* W       = (const float*)d_in[2];
    const float* att_w   = (const float*)d_in[3];
    const int*   src     = (const int*)d_in[4];
    const int*   dst     = (const int*)d_in[5];
    float* out = (float*)d_out;

    // Workspace layout:
    // Wh_b[25.6M u16 = 51.2MB] | p_src[400K f] | p_dst[400K f] |
    // head[400K i] | rec[3.2M int2 = 25.6MB] | Bpack[65536 u16]  total ~= 82 MB
    ushort* Wh_b  = (ushort*)d_ws;
    float*  p_src = (float*)(Wh_b + (size_t)M_SEG * OUT_F);
    float*  p_dst = p_src + M_SEG;
    int*    head  = (int*)(p_dst + M_SEG);
    int2*   rec   = (int2*)(head + M_SEG);
    ushort* Bpack = (ushort*)(rec + (size_t)D_CH * N_EDGE);

    bpack_kernel<<<dim3(32), 256, 0, stream>>>(W, Bpack);
    gemm_mfma_kernel<<<dim3((N_NODES + 63) / 64), 256, 0, stream>>>(
        feature, norm, Bpack, att_w, Wh_b, p_src, p_dst);

    hipMemsetAsync(head, 0xFF, (size_t)M_SEG * sizeof(int), stream);  // head = -1
    build_kernel<<<dim3(N_EDGE / 256, D_CH), 256, 0, stream>>>(src, dst, head, rec);
    agg_ll_kernel<<<dim3(M_SEG / (4 * CPW)), 256, 0, stream>>>(
        head, rec, p_src, p_dst, Wh_b, norm, out);
}

// Round 7
// 399.812 us; speedup vs baseline: 2.7811x; 1.1029x over previous
//
#include <hip/hip_runtime.h>

#define N_NODES 100000
#define IN_F    256
#define OUT_F   64
#define D_CH    4
#define N_EDGE  800000
#define M_SEG   (D_CH * N_NODES)          // 400000 segments
#define CPW     8                          // chains per wave

typedef __attribute__((ext_vector_type(8))) short short8;
typedef __attribute__((ext_vector_type(4))) float f32x4;

__device__ inline ushort f2bf(float f) {           // round-to-nearest-even
    union { float f; unsigned u; } v; v.f = f;
    unsigned b = v.u + 0x7FFFu + ((v.u >> 16) & 1u);
    return (ushort)(b >> 16);
}
__device__ inline float bf2f(ushort u) {
    union { unsigned u; float f; } v; v.u = ((unsigned)u) << 16;
    return v.f;
}
__device__ inline float bits2f(int b) {
    union { int i; float f; } v; v.i = b; return v.f;
}

// ---------------------------------------------------------------------------
// One-time: repack W (f32) into per-lane bf16 MFMA B-fragments.
// Fragment (i, ks, nt): lane l, elem j holds W[i][ks*32 + (l>>4)*8 + j][nt*16 + (l&15)]
// ---------------------------------------------------------------------------
__global__ __launch_bounds__(256) void bpack_kernel(
    const float* __restrict__ W, ushort* __restrict__ Bpack)
{
    const int t = blockIdx.x * 256 + threadIdx.x;      // 0 .. 8191
    if (t >= D_CH * 8 * 4 * 64) return;
    const int l  = t & 63;
    const int nt = (t >> 6) & 3;
    const int ks = (t >> 8) & 7;
    const int i  = t >> 11;
    const int n  = nt * 16 + (l & 15);
    const int k0 = ks * 32 + (l >> 4) * 8;
    ushort v[8];
#pragma unroll
    for (int j = 0; j < 8; ++j)
        v[j] = f2bf(W[((size_t)i * IN_F + k0 + j) * OUT_F + n]);
#pragma unroll
    for (int j = 0; j < 8; ++j)
        Bpack[(size_t)t * 8 + j] = v[j];
}

// ---------------------------------------------------------------------------
// MFMA GEMM + fused pvec epilogue.  (unchanged from R6)
// C/D layout (HW-verified): col = lane&15, row = (lane>>4)*4 + reg.
// ---------------------------------------------------------------------------
__global__ __launch_bounds__(256) void gemm_mfma_kernel(
    const float* __restrict__ feature, const float* __restrict__ norm,
    const ushort* __restrict__ Bpack, const float* __restrict__ att_w,
    ushort* __restrict__ Wh_b, float* __restrict__ p_src, float* __restrict__ p_dst)
{
    const int wv   = threadIdx.x >> 6;
    const int lane = threadIdx.x & 63;
    const int kg   = lane >> 4;
    const int cl   = lane & 15;
    const int r0   = blockIdx.x * 64 + wv * 16;

    const int rowm   = r0 + cl;
    const int rclamp = (rowm < N_NODES) ? rowm : (N_NODES - 1);
    const float* __restrict__ arow = feature + (size_t)rclamp * IN_F + kg * 8;
    short8 afrag[8];
#pragma unroll
    for (int ks = 0; ks < 8; ++ks) {
        const f32x4 x = *(const f32x4*)(arow + ks * 32);
        const f32x4 y = *(const f32x4*)(arow + ks * 32 + 4);
        short8 a;
        a[0] = (short)f2bf(x[0]); a[1] = (short)f2bf(x[1]);
        a[2] = (short)f2bf(x[2]); a[3] = (short)f2bf(x[3]);
        a[4] = (short)f2bf(y[0]); a[5] = (short)f2bf(y[1]);
        a[6] = (short)f2bf(y[2]); a[7] = (short)f2bf(y[3]);
        afrag[ks] = a;
    }

    float pa[4], pb[4];
#pragma unroll
    for (int nt = 0; nt < 4; ++nt) {
        pa[nt] = att_w[nt * 16 + cl];
        pb[nt] = att_w[OUT_F + nt * 16 + cl];
    }
    float nm[4];
    bool  rvld[4];
#pragma unroll
    for (int r = 0; r < 4; ++r) {
        const int rr = r0 + kg * 4 + r;
        rvld[r] = rr < N_NODES;
        nm[r] = rvld[r] ? norm[rr] : 0.f;
    }

    const short8* __restrict__ bp = (const short8*)Bpack;

    for (int i = 0; i < D_CH; ++i) {
        f32x4 acc[4];
#pragma unroll
        for (int nt = 0; nt < 4; ++nt) acc[nt] = (f32x4){0.f, 0.f, 0.f, 0.f};

#pragma unroll
        for (int ks = 0; ks < 8; ++ks) {
#pragma unroll
            for (int nt = 0; nt < 4; ++nt) {
                const short8 bf = bp[((((i * 8) + ks) * 4 + nt) << 6) + lane];
                acc[nt] = __builtin_amdgcn_mfma_f32_16x16x32_bf16(
                    afrag[ks], bf, acc[nt], 0, 0, 0);
            }
        }

        float ps[4] = {0.f, 0.f, 0.f, 0.f}, pd[4] = {0.f, 0.f, 0.f, 0.f};
#pragma unroll
        for (int nt = 0; nt < 4; ++nt) {
#pragma unroll
            for (int r = 0; r < 4; ++r) {
                const float v = acc[nt][r] * nm[r];
                const int rr = r0 + kg * 4 + r;
                if (rvld[r])
                    Wh_b[((size_t)i * N_NODES + rr) * OUT_F + nt * 16 + cl] = f2bf(v);
                ps[r] += v * pa[nt];
                pd[r] += v * pb[nt];
            }
        }
#pragma unroll
        for (int r = 0; r < 4; ++r) {
            float s1 = ps[r], s2 = pd[r];
#pragma unroll
            for (int off = 1; off < 16; off <<= 1) {
                s1 += __shfl_xor(s1, off, 64);
                s2 += __shfl_xor(s2, off, 64);
            }
            if (cl == 0 && rvld[r]) {
                const int rr = r0 + kg * 4 + r;
                p_src[i * N_NODES + rr] = s1;
                p_dst[i * N_NODES + rr] = s2;
            }
        }
    }
}

// ---------------------------------------------------------------------------
// Linked-list build with FULL records: rec[i][e] = {next, src, w_bits, 0}.
// Weight computed here (p arrays are 1.6 MB -> L2-resident random reads;
// exp rides a bandwidth-trivial pass). rec writes are SEQUENTIAL 16B.
// Must run after gemm (needs p_src/p_dst).
// ---------------------------------------------------------------------------
__global__ __launch_bounds__(256) void build_kernel(
    const int* __restrict__ src, const int* __restrict__ dst,
    const float* __restrict__ p_src, const float* __restrict__ p_dst,
    int* __restrict__ head, int4* __restrict__ rec)
{
    const int e = blockIdx.x * 256 + threadIdx.x;
    const int i = blockIdx.y;
    const int d = dst[(size_t)i * N_EDGE + e];
    const int s = src[(size_t)i * N_EDGE + e];
    float x = p_src[i * N_NODES + s] + p_dst[i * N_NODES + d];
    x = (x > 0.f) ? x : 0.2f * x;
    const float w = __expf(x);   // max-free softmax: logits O(4), no overflow
    union { float f; int i; } wb; wb.f = w;
    const int old = atomicExch(&head[i * N_NODES + d], e);
    rec[(size_t)i * N_EDGE + e] = make_int4(old, s, wb.i, 0);
}

// ---------------------------------------------------------------------------
// Aggregate via linked lists, CPW=8 chains/wave, ONE wait point per iteration.
// State entering iter k: (s,w) of current edge, en = next edge index.
// Iter k issues TWO independent loads per chain -- Wh gather for s, rec for en
// -- waits once, accumulates w*wh, ingests rec. 2 random loads + ~10 VALU
// ops per edge (was 3 loads + ~22 ops incl. exp).
// ---------------------------------------------------------------------------
__global__ __launch_bounds__(256) void agg_ll_kernel(
    const int* __restrict__ head, const int4* __restrict__ rec,
    const float* __restrict__ p_dst_unused, const ushort* __restrict__ Wh_b,
    const float* __restrict__ norm, float* __restrict__ out)
{
    const int wv   = threadIdx.x >> 6;
    const int lane = threadIdx.x & 63;
    const int g0   = (blockIdx.x * 4 + wv) * CPW;   // 8 consecutive segments
    // N_NODES % CPW == 0 -> all CPW segments share one channel.
    const int i  = g0 / N_NODES;
    const int n0 = g0 - i * N_NODES;

    const int4*   __restrict__ recb = rec + (size_t)i * N_EDGE;
    const ushort* __restrict__ whb  = Wh_b + (size_t)i * N_NODES * OUT_F + lane;

    // ---- prologue: ingest head edge of each chain ----
    int   s[CPW], en[CPW];
    float w[CPW], acc[CPW], z[CPW];
#pragma unroll
    for (int c = 0; c < CPW; ++c) {
        const int h = head[g0 + c];
        const int4 r = recb[(h >= 0) ? h : 0];
        const bool live = (h >= 0);
        s[c]   = live ? r.y : 0;
        w[c]   = live ? bits2f(r.z) : 0.f;
        en[c]  = live ? r.x : -1;
        acc[c] = 0.f;
        z[c]   = 0.f;
    }

    for (;;) {
        int pending = 0;
#pragma unroll
        for (int c = 0; c < CPW; ++c) {
            // two independent loads -> single wait covers both
            const float wh = bf2f(whb[(unsigned)(s[c] * OUT_F)]);
            const int4  r  = recb[(en[c] >= 0) ? en[c] : 0];

            acc[c] += w[c] * wh;     // w==0 for dead chains: harmless
            z[c]   += w[c];

            const int live = (en[c] >= 0);
            s[c]  = live ? r.y : 0;
            w[c]  = live ? bits2f(r.z) : 0.f;
            en[c] = live ? r.x : -1;
            pending |= live;
        }
        if (!pending) break;
    }

#pragma unroll
    for (int c = 0; c < CPW; ++c) {
        const int n = n0 + c;
        float v = (z[c] > 0.f) ? (acc[c] / z[c]) * norm[n] : 0.f;
        out[(size_t)n * (D_CH * OUT_F) + i * OUT_F + lane] = (v > 0.f) ? v : 0.f;
    }
}

// ---------------------------------------------------------------------------
extern "C" void kernel_launch(void* const* d_in, const int* in_sizes, int n_in,
                              void* d_out, int out_size, void* d_ws, size_t ws_size,
                              hipStream_t stream)
{
    const float* feature = (const float*)d_in[0];
    const float* norm    = (const float*)d_in[1];
    const float* W       = (const float*)d_in[2];
    const float* att_w   = (const float*)d_in[3];
    const int*   src     = (const int*)d_in[4];
    const int*   dst     = (const int*)d_in[5];
    float* out = (float*)d_out;

    // Workspace layout:
    // Wh_b[25.6M u16 = 51.2MB] | p_src[400K f] | p_dst[400K f] |
    // head[400K i] | rec[3.2M int4 = 51.2MB] | Bpack[65536 u16]  total ~= 108 MB
    ushort* Wh_b  = (ushort*)d_ws;
    float*  p_src = (float*)(Wh_b + (size_t)M_SEG * OUT_F);
    float*  p_dst = p_src + M_SEG;
    int*    head  = (int*)(p_dst + M_SEG);
    int4*   rec   = (int4*)(head + M_SEG);
    ushort* Bpack = (ushort*)(rec + (size_t)D_CH * N_EDGE);

    bpack_kernel<<<dim3(32), 256, 0, stream>>>(W, Bpack);
    gemm_mfma_kernel<<<dim3((N_NODES + 63) / 64), 256, 0, stream>>>(
        feature, norm, Bpack, att_w, Wh_b, p_src, p_dst);

    hipMemsetAsync(head, 0xFF, (size_t)M_SEG * sizeof(int), stream);  // head = -1
    build_kernel<<<dim3(N_EDGE / 256, D_CH), 256, 0, stream>>>(
        src, dst, p_src, p_dst, head, rec);
    agg_ll_kernel<<<dim3(M_SEG / (4 * CPW)), 256, 0, stream>>>(
        head, rec, p_dst, Wh_b, norm, out);
}